// Round 1
// baseline (631.776 us; speedup 1.0000x reference)
//
#include <hip/hip_runtime.h>
#include <hip/hip_fp16.h>

#define BATCH 16
#define CH    64
#define TLEN  200
#define NP    30
#define HID   128
#define G4    512            // 4*HID
#define NSEQ  (BATCH * NP)   // 480

__device__ __forceinline__ float dot4(float4 a, float4 b) {
    return a.x * b.x + a.y * b.y + a.z * b.z + a.w * b.w;
}

__device__ __forceinline__ float sigm_fast(float x) {
    // 1/(1+exp(-x)); v_exp + v_rcp. exp overflow -> inf -> rcp -> 0 (correct limit).
    return __builtin_amdgcn_rcpf(1.0f + __expf(-x));
}

__device__ __forceinline__ float tanh_fast(float x) {
    float xc = fminf(15.0f, fmaxf(-15.0f, x));   // clamp: avoid inf/inf
    float e = __expf(2.0f * xc);
    return (e - 1.0f) * __builtin_amdgcn_rcpf(e + 1.0f);
}

// ---------------------------------------------------------------------------
// Phase 1: xg[n][t][g] = sum_c x[b][c][t][p] * W_ih[g][c] + b_ih[g] + b_hh[g]
// n = b*NP + p. One block per (t, b). x slice staged via LDS (x layout is
// hostile: stride 30 along t, 6000 along c). W_ih row in registers.
// ---------------------------------------------------------------------------
template <typename XT>
__global__ __launch_bounds__(512, 2) void xg_kernel(
    const float* __restrict__ x, const float* __restrict__ W_ih,
    const float* __restrict__ b_ih, const float* __restrict__ b_hh,
    XT* __restrict__ xg)
{
    const int t   = blockIdx.x;   // 0..199
    const int b   = blockIdx.y;   // 0..15
    const int tid = threadIdx.x;  // 0..511

    __shared__ float xs[NP][CH];  // [p][c], row 256B -> float4-aligned

    {   // cooperative load of x[b, :, t, :]  (64 rows of 30 contiguous floats)
        const int c = tid >> 3;       // 0..63
        const int l = tid & 7;
        const float* xr = x + ((size_t)(b * CH + c) * TLEN + t) * NP;
        for (int p = l; p < NP; p += 8) xs[p][c] = xr[p];
    }
    __syncthreads();

    const int g = tid;  // gate row 0..511
    float4 w[16];
    const float4* wr = (const float4*)(W_ih + (size_t)g * CH);
#pragma unroll
    for (int k = 0; k < 16; ++k) w[k] = wr[k];
    const float bias = b_ih[g] + b_hh[g];

    for (int p = 0; p < NP; ++p) {
        const float4* xv = (const float4*)(xs[p]);
        float a0 = 0.f, a1 = 0.f, a2 = 0.f, a3 = 0.f;
#pragma unroll
        for (int k = 0; k < 16; k += 4) {
            a0 += dot4(w[k + 0], xv[k + 0]);
            a1 += dot4(w[k + 1], xv[k + 1]);
            a2 += dot4(w[k + 2], xv[k + 2]);
            a3 += dot4(w[k + 3], xv[k + 3]);
        }
        const float acc = bias + ((a0 + a1) + (a2 + a3));
        const int n = b * NP + p;
        xg[((size_t)n * TLEN + t) * G4 + g] = (XT)acc;  // coalesced: g contiguous
    }
}

// ---------------------------------------------------------------------------
// Phase 2: recurrent LSTM. One block = 2 sequences (240 blocks ~ 1/CU).
// Thread g holds W_hh row g in 128 VGPRs, computes gate g for both sequences.
// h, c, gates live in LDS (h reads are wave-broadcast -> conflict-free).
// ---------------------------------------------------------------------------
template <typename XT>
__global__ __launch_bounds__(512, 2) void lstm_kernel(
    const XT* __restrict__ xg, const float* __restrict__ W_hh,
    const float* __restrict__ W_fc, const float* __restrict__ b_fc,
    float* __restrict__ out)
{
    const int pair = blockIdx.x;      // 0..239
    const int n0 = pair * 2;
    const int n1 = n0 + 1;
    const int tid = threadIdx.x;      // 0..511 (= gate index)

    __shared__ float hs[2][HID];
    __shared__ float cs[2][HID];
    __shared__ float gl[2][G4];

    if (tid < 2 * HID) {
        hs[tid >> 7][tid & 127] = 0.0f;
        cs[tid >> 7][tid & 127] = 0.0f;
    }

    float4 w[32];
    const float4* wr = (const float4*)(W_hh + (size_t)tid * HID);
#pragma unroll
    for (int k = 0; k < 32; ++k) w[k] = wr[k];

    const XT* p0 = xg + (size_t)n0 * TLEN * G4 + tid;
    const XT* p1 = xg + (size_t)n1 * TLEN * G4 + tid;
    float xa = (float)p0[0];
    float xb = (float)p1[0];
    __syncthreads();

    for (int t = 0; t < TLEN; ++t) {
        // prefetch next step's input gates (independent of LDS deps)
        float nxa = 0.f, nxb = 0.f;
        if (t + 1 < TLEN) {
            nxa = (float)p0[(size_t)(t + 1) * G4];
            nxb = (float)p1[(size_t)(t + 1) * G4];
        }

        const float4* h0 = (const float4*)hs[0];
        const float4* h1 = (const float4*)hs[1];
        float d0a = 0.f, d0b = 0.f, d1a = 0.f, d1b = 0.f;
#pragma unroll
        for (int k = 0; k < 32; k += 2) {
            float4 ha = h0[k], hb = h0[k + 1];
            float4 ga = h1[k], gb = h1[k + 1];
            d0a += dot4(w[k], ha);
            d0b += dot4(w[k + 1], hb);
            d1a += dot4(w[k], ga);
            d1b += dot4(w[k + 1], gb);
        }
        gl[0][tid] = xa + (d0a + d0b);
        gl[1][tid] = xb + (d1a + d1b);
        __syncthreads();

        if (tid < 2 * HID) {
            const int s = tid >> 7, j = tid & 127;
            const float gi = gl[s][j];
            const float gf = gl[s][HID + j];
            const float gg = gl[s][2 * HID + j];
            const float go = gl[s][3 * HID + j];
            const float i = sigm_fast(gi);
            const float f = sigm_fast(gf);
            const float gt = tanh_fast(gg);
            const float o = sigm_fast(go);
            const float cn = f * cs[s][j] + i * gt;
            cs[s][j] = cn;
            hs[s][j] = o * tanh_fast(cn);
        }
        __syncthreads();
        xa = nxa;
        xb = nxb;
    }

    // epilogue: out[n][ch] = h . W_fc[ch] + b_fc[ch]
    if (tid < 2 * CH) {
        const int s = tid >> 6, ch = tid & 63;
        const float4* wf = (const float4*)(W_fc + (size_t)ch * HID);
        const float4* hv = (const float4*)hs[s];
        float a0 = 0.f, a1 = 0.f;
#pragma unroll
        for (int j = 0; j < 32; j += 2) {
            a0 += dot4(wf[j], hv[j]);
            a1 += dot4(wf[j + 1], hv[j + 1]);
        }
        out[(size_t)(n0 + s) * CH + ch] = a0 + a1 + b_fc[ch];
    }
}

extern "C" void kernel_launch(void* const* d_in, const int* in_sizes, int n_in,
                              void* d_out, int out_size, void* d_ws, size_t ws_size,
                              hipStream_t stream) {
    (void)in_sizes; (void)n_in; (void)out_size;
    const float* x    = (const float*)d_in[0];
    const float* W_ih = (const float*)d_in[1];
    const float* W_hh = (const float*)d_in[2];
    const float* b_ih = (const float*)d_in[3];
    const float* b_hh = (const float*)d_in[4];
    const float* W_fc = (const float*)d_in[5];
    const float* b_fc = (const float*)d_in[6];
    float* out = (float*)d_out;

    const size_t need_f32 = (size_t)NSEQ * TLEN * G4 * sizeof(float);  // 196.6 MB
    if (ws_size >= need_f32) {
        float* xg = (float*)d_ws;
        xg_kernel<float><<<dim3(TLEN, BATCH), 512, 0, stream>>>(x, W_ih, b_ih, b_hh, xg);
        lstm_kernel<float><<<NSEQ / 2, 512, 0, stream>>>(xg, W_hh, W_fc, b_fc, out);
    } else {
        // fallback: fp16 xg staging (98.3 MB); fp32 accumulate both phases
        __half* xg = (__half*)d_ws;
        xg_kernel<__half><<<dim3(TLEN, BATCH), 512, 0, stream>>>(x, W_ih, b_ih, b_hh, xg);
        lstm_kernel<__half><<<NSEQ / 2, 512, 0, stream>>>(xg, W_hh, W_fc, b_fc, out);
    }
}